// Round 17
// baseline (2442.281 us; speedup 1.0000x reference)
//
#include <hip/hip_runtime.h>
#include <hip/hip_cooperative_groups.h>
#include <math.h>

namespace cg = cooperative_groups;

#define TT   256
#define DD   2048
#define VV   32000
#define NBLK 4
#define CC   512
#define RR   32
#define MTT  3
#define NBAT 2
#define NTOK 512   // NBAT*TT

typedef unsigned int u32;
typedef unsigned short ushort_t;
typedef __attribute__((ext_vector_type(8))) short s16x8;
typedef __attribute__((ext_vector_type(4))) float f32x4;

__device__ __forceinline__ float sigm(float x){ return 1.0f/(1.0f+expf(-x)); }
__device__ __forceinline__ float gelu(float v){
  return 0.5f * v * (1.f + erff(v * 0.70710678118654752f));
}

__device__ __forceinline__ ushort_t f2bf(float f){
  u32 u = __float_as_uint(f);
  u32 r = (u + 0x7fffu + ((u >> 16) & 1u)) >> 16;
  return (ushort_t)r;
}
__device__ __forceinline__ float bf2f(ushort_t u){
  return __uint_as_float(((u32)u) << 16);
}

__device__ __forceinline__ void async_copy16(void* lds, const void* g){
  __builtin_amdgcn_global_load_lds((const __attribute__((address_space(1))) u32*)g,
                                   (__attribute__((address_space(3))) u32*)lds, 16, 0, 0);
}

__device__ __forceinline__ float block_sum256(float v){
  #pragma unroll
  for (int off = 32; off > 0; off >>= 1) v += __shfl_down(v, off);
  __shared__ float sh[4];
  __syncthreads();
  if ((threadIdx.x & 63) == 0) sh[threadIdx.x >> 6] = v;
  __syncthreads();
  return sh[0] + sh[1] + sh[2] + sh[3];
}

// fp32 -> bf16 for two tensors in one launch
__global__ __launch_bounds__(256) void cvt2_kernel(const float* __restrict__ a,
    ushort_t* __restrict__ oa, long na4,
    const float* __restrict__ b, ushort_t* __restrict__ ob, long nb4){
  long i = (long)blockIdx.x * 256 + threadIdx.x;
  long stride = (long)gridDim.x * 256;
  long tot = na4 + nb4;
  for (; i < tot; i += stride){
    const float* src = (i < na4) ? a : b;
    ushort_t* dst = (i < na4) ? oa : ob;
    long k = (i < na4) ? i : i - na4;
    float4 v = ((const float4*)src)[k];
    ushort4 o;
    o.x = f2bf(v.x); o.y = f2bf(v.y); o.z = f2bf(v.z); o.w = f2bf(v.w);
    ((ushort4*)dst)[k] = o;
  }
}

// one kernel for all sign-vector prep + Adec
__global__ __launch_bounds__(256) void sign_prep_kernel(
    const float* __restrict__ bv_q, const float* __restrict__ bv_k,
    const float* __restrict__ bv_v, const float* __restrict__ query_bind,
    const float* __restrict__ rules, const float* __restrict__ decay_logit,
    float* __restrict__ SQK, float* __restrict__ SV, float* __restrict__ SQB,
    ushort_t* __restrict__ RLSb, ushort_t* __restrict__ Adec){
  int b = blockIdx.x;
  if (b >= 3*NBLK + NBLK*RR){
    int e = b - (3*NBLK + NBLK*RR);
    int i = e >> 8, t = e & (TT - 1), s = threadIdx.x;
    float decay = sigm(decay_logit[i]);
    float l2 = log2f(decay);
    int ex = t - s;
    float v = (ex < 0) ? 0.f : exp2f((float)ex * l2);
    Adec[((size_t)i*TT + t)*TT + s] = f2bf(v);
    return;
  }
  if (b < NBLK){
    const float* q = bv_q + (size_t)b * DD;
    const float* k = bv_k + (size_t)b * DD;
    float sq = 0.f, sk = 0.f;
    #pragma unroll
    for (int j = 0; j < 8; j++){
      int d = threadIdx.x + j*256;
      sq += fabsf(q[d]); sk += fabsf(k[d]);
    }
    float aq = block_sum256(sq) * (1.f/DD);
    float ak = block_sum256(sk) * (1.f/DD);
    float a2 = aq * ak;
    float* o = SQK + (size_t)b * DD;
    #pragma unroll
    for (int j = 0; j < 8; j++){
      int d = threadIdx.x + j*256;
      o[d] = ((q[d] < 0.f) != (k[d] < 0.f)) ? -a2 : a2;
    }
    return;
  }
  const float* w; float* of = nullptr; ushort_t* ob = nullptr;
  if (b < 2*NBLK){ w = bv_v + (size_t)(b - NBLK) * DD; of = SV + (size_t)(b - NBLK) * DD; }
  else if (b < 3*NBLK){ w = query_bind + (size_t)(b - 2*NBLK) * DD; of = SQB + (size_t)(b - 2*NBLK) * DD; }
  else { int r = b - 3*NBLK; w = rules + (size_t)r * DD; ob = RLSb + (size_t)r * DD; }
  float s = 0.f;
  #pragma unroll
  for (int j = 0; j < 8; j++) s += fabsf(w[threadIdx.x + j*256]);
  float a = block_sum256(s) * (1.f/DD);
  #pragma unroll
  for (int j = 0; j < 8; j++){
    int d = threadIdx.x + j*256;
    float v = (w[d] < 0.f) ? -a : a;
    if (of) of[d] = v;
    else    ob[d] = f2bf(v);
  }
}

__global__ __launch_bounds__(256) void encode_kernel(const int* __restrict__ idx,
    const float* __restrict__ cb, float* __restrict__ X, ushort_t* __restrict__ Xrb){
  int token = blockIdx.x;
  int t = token & (TT - 1);
  size_t row = (size_t)idx[token] * DD;
  float s = 0.f;
  #pragma unroll
  for (int j = 0; j < 8; j++) s += fabsf(cb[row + threadIdx.x + j*256]);
  float a = block_sum256(s) * (1.f/DD);
  #pragma unroll
  for (int j = 0; j < 8; j++){
    int d = threadIdx.x + j*256;
    float w = cb[row + ((d - t) & (DD - 1))];
    float v = (w < 0.f) ? -a : a;
    X[(size_t)token * DD + d] = v;
    Xrb[(size_t)token * DD + d] = f2bf(v);
  }
}

// y=LN(A[row])*g+be; contiguous 8 elems/thread, fully vectorized loads/stores.
__global__ __launch_bounds__(256) void ln_kernel(const float* __restrict__ A,
    const float* __restrict__ g, const float* __restrict__ be,
    float* __restrict__ out, ushort_t* __restrict__ outb,
    const float* __restrict__ qscale, ushort_t* __restrict__ outq,
    const float* __restrict__ vscale, ushort_t* __restrict__ outv){
  size_t row = blockIdx.x;
  const float* a = A + row * DD;
  int d0 = threadIdx.x * 8;
  float v[8];
  *(float4*)&v[0] = *(const float4*)(a + d0);
  *(float4*)&v[4] = *(const float4*)(a + d0 + 4);
  float s = 0.f, ss = 0.f;
  #pragma unroll
  for (int j = 0; j < 8; j++){ s += v[j]; ss += v[j]*v[j]; }
  float mean = block_sum256(s) * (1.f/DD);
  float var  = block_sum256(ss) * (1.f/DD) - mean*mean;
  float inv  = rsqrtf(var + 1e-5f);
  float gv[8], bv[8];
  *(float4*)&gv[0] = *(const float4*)(g + d0);
  *(float4*)&gv[4] = *(const float4*)(g + d0 + 4);
  *(float4*)&bv[0] = *(const float4*)(be + d0);
  *(float4*)&bv[4] = *(const float4*)(be + d0 + 4);
  float y[8];
  #pragma unroll
  for (int j = 0; j < 8; j++) y[j] = (v[j] - mean) * inv * gv[j] + bv[j];
  if (out){
    *(float4*)(out + row*DD + d0)     = *(float4*)&y[0];
    *(float4*)(out + row*DD + d0 + 4) = *(float4*)&y[4];
  }
  if (outb){
    s16x8 o;
    #pragma unroll
    for (int j = 0; j < 8; j++) o[j] = (short)f2bf(y[j]);
    *(s16x8*)(outb + row*DD + d0) = o;
  }
  if (outq){
    float qv[8];
    *(float4*)&qv[0] = *(const float4*)(qscale + d0);
    *(float4*)&qv[4] = *(const float4*)(qscale + d0 + 4);
    s16x8 o;
    #pragma unroll
    for (int j = 0; j < 8; j++) o[j] = (short)f2bf(y[j] * qv[j]);
    *(s16x8*)(outq + row*DD + d0) = o;
  }
  if (outv){
    float vv[8];
    *(float4*)&vv[0] = *(const float4*)(vscale + d0);
    *(float4*)&vv[4] = *(const float4*)(vscale + d0 + 4);
    s16x8 o;
    #pragma unroll
    for (int j = 0; j < 8; j++) o[j] = (short)f2bf(y[j] * vv[j]);
    *(s16x8*)(outv + row*DD + d0) = o;
  }
}

// Mega-fused: LN_attn + logic + gate + LN_logic + ctrl-LN. One block per token.
__global__ __launch_bounds__(256) void fuse_logic_kernel(const float* __restrict__ T0,
    const ushort_t* __restrict__ RLSi, const float* __restrict__ SQBi,
    const float* __restrict__ g2, const float* __restrict__ b2,
    const float* __restrict__ gate_ptr,
    const float* __restrict__ g3, const float* __restrict__ b3,
    const float* __restrict__ g4, const float* __restrict__ b4,
    float* __restrict__ X, ushort_t* __restrict__ T1b){
  __shared__ float sh[256*33];
  __shared__ float red[8*32];
  __shared__ float rwsh[32];
  const float RSD = 0.022097086912079608f;
  int tid = threadIdx.x;
  size_t tok = blockIdx.x;
  const float* a = T0 + tok * DD;
  int d0 = tid * 8;
  float v[8];
  *(float4*)&v[0] = *(const float4*)(a + d0);
  *(float4*)&v[4] = *(const float4*)(a + d0 + 4);
  float s = 0.f, ss = 0.f;
  #pragma unroll
  for (int j = 0; j < 8; j++){ s += v[j]; ss += v[j]*v[j]; }
  float mean = block_sum256(s) * (1.f/DD);
  float var  = block_sum256(ss) * (1.f/DD) - mean*mean;
  float inv  = rsqrtf(var + 1e-5f);
  float g2v[8], b2v[8], sqv[8];
  *(float4*)&g2v[0] = *(const float4*)(g2 + d0);
  *(float4*)&g2v[4] = *(const float4*)(g2 + d0 + 4);
  *(float4*)&b2v[0] = *(const float4*)(b2 + d0);
  *(float4*)&b2v[4] = *(const float4*)(b2 + d0 + 4);
  *(float4*)&sqv[0] = *(const float4*)(SQBi + d0);
  *(float4*)&sqv[4] = *(const float4*)(SQBi + d0 + 4);
  float y2[8], xq[8];
  #pragma unroll
  for (int j = 0; j < 8; j++){
    y2[j] = (v[j] - mean) * inv * g2v[j] + b2v[j];
    xq[j] = y2[j] * sqv[j];
  }
  float aa[32];
  #pragma unroll 4
  for (int r = 0; r < 32; r++){
    s16x8 rv = *(const s16x8*)(RLSi + (size_t)r*DD + d0);
    float t = 0.f;
    #pragma unroll
    for (int j = 0; j < 8; j++)
      t = fmaf(xq[j], bf2f((ushort_t)rv[j]), t);
    aa[r] = t;
  }
  #pragma unroll
  for (int r = 0; r < 32; r++) sh[tid*33 + r] = aa[r];
  __syncthreads();
  {
    int r = tid & 31, gg = tid >> 5;
    float t = 0.f;
    #pragma unroll 8
    for (int i = 0; i < 32; i++) t += sh[(gg*32 + i)*33 + r];
    red[gg*32 + r] = t;
  }
  __syncthreads();
  if (tid < 32){
    float t = 0.f;
    #pragma unroll
    for (int gg = 0; gg < 8; gg++) t += red[gg*32 + tid];
    rwsh[tid] = sigm(4.f * RSD * t);
  }
  __syncthreads();
  float gate = sigm(*gate_ptr);
  float acc8[8] = {};
  #pragma unroll 4
  for (int r = 0; r < 32; r++){
    s16x8 rv = *(const s16x8*)(RLSi + (size_t)r*DD + d0);
    float w = rwsh[r];
    #pragma unroll
    for (int j = 0; j < 8; j++)
      acc8[j] = fmaf(w, bf2f((ushort_t)rv[j]), acc8[j]);
  }
  float p3[8]; s = 0.f; ss = 0.f;
  #pragma unroll
  for (int j = 0; j < 8; j++){
    float lo = y2[j] * acc8[j];
    p3[j] = y2[j] + gate * (lo - y2[j]);
    s += p3[j]; ss += p3[j]*p3[j];
  }
  mean = block_sum256(s) * (1.f/DD);
  var  = block_sum256(ss) * (1.f/DD) - mean*mean;
  inv  = rsqrtf(var + 1e-5f);
  float g3v[8], b3v[8];
  *(float4*)&g3v[0] = *(const float4*)(g3 + d0);
  *(float4*)&g3v[4] = *(const float4*)(g3 + d0 + 4);
  *(float4*)&b3v[0] = *(const float4*)(b3 + d0);
  *(float4*)&b3v[4] = *(const float4*)(b3 + d0 + 4);
  float y3[8]; s = 0.f; ss = 0.f;
  #pragma unroll
  for (int j = 0; j < 8; j++){
    y3[j] = (p3[j] - mean) * inv * g3v[j] + b3v[j];
    s += y3[j]; ss += y3[j]*y3[j];
  }
  *(float4*)(X + tok*DD + d0)     = *(float4*)&y3[0];
  *(float4*)(X + tok*DD + d0 + 4) = *(float4*)&y3[4];
  mean = block_sum256(s) * (1.f/DD);
  var  = block_sum256(ss) * (1.f/DD) - mean*mean;
  inv  = rsqrtf(var + 1e-5f);
  float g4v[8], b4v[8];
  *(float4*)&g4v[0] = *(const float4*)(g4 + d0);
  *(float4*)&g4v[4] = *(const float4*)(g4 + d0 + 4);
  *(float4*)&b4v[0] = *(const float4*)(b4 + d0);
  *(float4*)&b4v[4] = *(const float4*)(b4 + d0 + 4);
  s16x8 o;
  #pragma unroll
  for (int j = 0; j < 8; j++)
    o[j] = (short)f2bf((y3[j] - mean) * inv * g4v[j] + b4v[j]);
  *(s16x8*)(T1b + tok*DD + d0) = o;
}

// Thought-loop glue: contiguous vectorized
__global__ __launch_bounds__(256) void tl_kernel(const float* __restrict__ Xr,
    float* __restrict__ H, const float* __restrict__ gate_ptr,
    const float* __restrict__ g, const float* __restrict__ be,
    const float* __restrict__ pos,
    float* __restrict__ outX, ushort_t* __restrict__ outXb){
  size_t row = blockIdx.x;
  float gate = gate_ptr ? sigm(*gate_ptr) : 1.f;
  int d0 = threadIdx.x * 8;
  float xr[8];
  *(float4*)&xr[0] = *(const float4*)(Xr + row*DD + d0);
  *(float4*)&xr[4] = *(const float4*)(Xr + row*DD + d0 + 4);
  float v[8]; float s = 0.f, ss = 0.f;
  if (gate_ptr){
    float hv[8];
    *(float4*)&hv[0] = *(const float4*)(H + row*DD + d0);
    *(float4*)&hv[4] = *(const float4*)(H + row*DD + d0 + 4);
    #pragma unroll
    for (int j = 0; j < 8; j++) v[j] = hv[j] + gate * (xr[j] - hv[j]);
  } else {
    #pragma unroll
    for (int j = 0; j < 8; j++) v[j] = xr[j];
  }
  *(float4*)(H + row*DD + d0)     = *(float4*)&v[0];
  *(float4*)(H + row*DD + d0 + 4) = *(float4*)&v[4];
  #pragma unroll
  for (int j = 0; j < 8; j++){ s += v[j]; ss += v[j]*v[j]; }
  float mean = block_sum256(s) * (1.f/DD);
  float var  = block_sum256(ss) * (1.f/DD) - mean*mean;
  float inv  = rsqrtf(var + 1e-5f);
  float gv[8], bv[8];
  *(float4*)&gv[0] = *(const float4*)(g + d0);
  *(float4*)&gv[4] = *(const float4*)(g + d0 + 4);
  *(float4*)&bv[0] = *(const float4*)(be + d0);
  *(float4*)&bv[4] = *(const float4*)(be + d0 + 4);
  float y[8];
  #pragma unroll
  for (int j = 0; j < 8; j++) y[j] = (v[j] - mean) * inv * gv[j] + bv[j];
  if (pos){
    float pv[8];
    *(float4*)&pv[0] = *(const float4*)(pos + d0);
    *(float4*)&pv[4] = *(const float4*)(pos + d0 + 4);
    #pragma unroll
    for (int j = 0; j < 8; j++) y[j] += pv[j];
  }
  if (outX){
    *(float4*)(outX + row*DD + d0)     = *(float4*)&y[0];
    *(float4*)(outX + row*DD + d0 + 4) = *(float4*)&y[4];
  }
  if (outXb){
    s16x8 o;
    #pragma unroll
    for (int j = 0; j < 8; j++) o[j] = (short)f2bf(y[j]);
    *(s16x8*)(outXb + row*DD + d0) = o;
  }
}

// ===================== bf16 MFMA NT GEMM (single-buffer, general) =====================
template<int BM, int BN, int ACT, bool OUTBF>
__global__ __launch_bounds__(256) void gemm_nt(const ushort_t* __restrict__ A,
    const ushort_t* __restrict__ B, void* __restrict__ Cv,
    int K, int lda, int ldb, int ldc,
    long sA, long sB, long sC,
    const float* __restrict__ bias,
    const float* __restrict__ res, ushort_t* __restrict__ mirror)
{
  constexpr int FM = BM / 32;
  constexpr int FN = BN / 32;
  __shared__ __align__(16) ushort_t shA[BM * 64];
  __shared__ __align__(16) ushort_t shB[BN * 64];
  const int tid = threadIdx.x;
  const int l = tid & 63, w = tid >> 6;
  const int wr = w >> 1, wc = w & 1;
  const int row0 = blockIdx.y * BM, col0 = blockIdx.x * BN;
  const int zb = blockIdx.z;

  A += (size_t)zb * sA;
  B += (size_t)zb * sB;

  f32x4 acc[FM][FN] = {};

  for (int kt = 0; kt < K; kt += 64){
    #pragma unroll
    for (int i = 0; i < BM/32; i++){
      int o = i*4096 + tid*16;
      int r = o >> 7, c = (o >> 4) & 7;
      int lc = c ^ (r & 7);
      async_copy16((char*)shA + o, A + (size_t)(row0 + r) * lda + kt + lc*8);
    }
    #pragma unroll
    for (int i = 0; i < BN/32; i++){
      int o = i*4096 + tid*16;
      int r = o >> 7, c = (o >> 4) & 7;
      int lc = c ^ (r & 7);
      async_copy16((char*)shB + o, B + (size_t)(col0 + r) * ldb + kt + lc*8);
    }
    __syncthreads();
    #pragma unroll
    for (int kk = 0; kk < 2; kk++){
      s16x8 af[FM], bfr[FN];
      #pragma unroll
      for (int mi = 0; mi < FM; mi++){
        int r = wr*(BM/2) + mi*16 + (l & 15);
        int c = kk*4 + (l >> 4);
        af[mi] = *(const s16x8*)((const char*)shA + r*128 + ((c ^ (r & 7)) << 4));
      }
      #pragma unroll
      for (int ni = 0; ni < FN; ni++){
        int r = wc*(BN/2) + ni*16 + (l & 15);
        int c = kk*4 + (l >> 4);
        bfr[ni] = *(const s16x8*)((const char*)shB + r*128 + ((c ^ (r & 7)) << 4));
      }
      #pragma unroll
      for (int mi = 0; mi < FM; mi++)
        #pragma unroll
        for (int ni = 0; ni < FN; ni++)
          acc[mi][ni] = __builtin_amdgcn_mfma_f32_16x16x32_bf16(af[mi], bfr[ni], acc[mi][ni], 0, 0, 0);
    }
    __syncthreads();
  }

  float* Cf = (float*)Cv + (size_t)zb * sC;
  ushort_t* Cb = (ushort_t*)Cv + (size_t)zb * sC;
  const float* resz = res ? res + (size_t)zb * sC : nullptr;
  #pragma unroll
  for (int mi = 0; mi < FM; mi++){
    #pragma unroll
    for (int ni = 0; ni < FN; ni++){
      #pragma unroll
      for (int j = 0; j < 4; j++){
        int m = row0 + wr*(BM/2) + mi*16 + (l >> 4)*4 + j;
        int n = col0 + wc*(BN/2) + ni*16 + (l & 15);
        float v = acc[mi][ni][j];
        if (bias) v += bias[n];
        if (ACT == 2) v = gelu(v);
        if (resz) v += resz[(size_t)m * ldc + n];
        if (OUTBF) Cb[(size_t)m * ldc + n] = f2bf(v);
        else       Cf[(size_t)m * ldc + n] = v;
        if (mirror) mirror[(size_t)m * ldc + n] = f2bf(v);
      }
    }
  }
}

// ===================== bf16 MFMA NN GEMM (register-staged transposed B) =====================
// tri!=0: A lower-triangular — K-loop stops at row0+64 (exact).
__global__ __launch_bounds__(256) void gemm_nn(const ushort_t* __restrict__ A,
    const ushort_t* __restrict__ B, float* __restrict__ C,
    int K, int lda, int ldb, int ldc,
    long sA, long sB, long sC,
    const float* __restrict__ res, int tri)
{
  __shared__ __align__(16) ushort_t shA[64 * 64];
  __shared__ __align__(16) ushort_t shB[64 * 64];
  const int tid = threadIdx.x;
  const int l = tid & 63, w = tid >> 6;
  const int wr = w >> 1, wc = w & 1;
  const int row0 = blockIdx.y * 64, col0 = blockIdx.x * 64;
  A += (size_t)blockIdx.z * sA;
  B += (size_t)blockIdx.z * sB;

  const int kb = tid & 63;
  const int nb0 = (tid >> 6) * 8;
  const int kend = tri ? (row0 + 64 < K ? row0 + 64 : K) : K;

  f32x4 acc[2][2] = {};

  for (int kt = 0; kt < kend; kt += 64){
    #pragma unroll
    for (int i = 0; i < 2; i++){
      int o = i*4096 + tid*16;
      int r = o >> 7, c = (o >> 4) & 7;
      int lc = c ^ (r & 7);
      async_copy16((char*)shA + o, A + (size_t)(row0 + r) * lda + kt + lc*8);
    }
    #pragma unroll
    for (int i = 0; i < 2; i++){
      int n0 = nb0 + i*32;
      s16x8 v = *(const s16x8*)(B + (size_t)(kt + kb) * ldb + col0 + n0);
      #pragma unroll
      for (int j = 0; j < 8; j++){
        int n = n0 + j;
        int off = n*128 + (((kb >> 3) ^ (n & 7)) << 4) + ((kb & 7) << 1);
        *(ushort_t*)((char*)shB + off) = (ushort_t)v[j];
      }
    }
    __syncthreads();
    #pragma unroll
    for (int kk = 0; kk < 2; kk++){
      s16x8 af[2], bfr[2];
      #pragma unroll
      for (int mi = 0; mi < 2; mi++){
        int r = wr*32 + mi*16 + (l & 15);
        int c = kk*4 + (l >> 4);
        af[mi] = *(const s16x8*)((const char*)shA + r*128 + ((c ^ (r & 7)) << 4));
      }
      #pragma unroll
      for (int ni = 0; ni < 2; ni++){
        int r = wc*32 + ni*16 + (l & 15);
        int c = kk*4 + (l >> 4);
        bfr[ni] = *(const s16x8*)((const char*)shB + r*128 + ((c ^ (r & 7)) << 4));
      }
      #pragma unroll
      for (int mi = 0; mi < 2; mi++)
        #pragma unroll
        for (int ni = 0; ni < 2; ni++)
          acc[mi][ni] = __builtin_amdgcn_mfma_f32_16x16x32_bf16(af[mi], bfr[ni], acc[mi][ni], 0, 0, 0);
    }
    __syncthreads();
  }

  float* Cf = C + (size_t)blockIdx.z * sC;
  const float* resz = res ? res + (size_t)blockIdx.z * sC : nullptr;
  #pragma unroll
  for (int mi = 0; mi < 2; mi++)
    #pragma unroll
    for (int ni = 0; ni < 2; ni++)
      #pragma unroll
      for (int j = 0; j < 4; j++){
        int m = row0 + wr*32 + mi*16 + (l >> 4)*4 + j;
        int n = col0 + wc*32 + ni*16 + (l & 15);
        float v = acc[mi][ni][j];
        if (resz) v += resz[(size_t)m * ldc + n];
        Cf[(size_t)m * ldc + n] = v;
      }
}

// ===================== cooperative: scores split-K gemm + grid.sync + reduce =====================
// grid (4,4,16): z = zb*8+zk. Phase A: partial Xqb.Xb^T (causal tiles skip). Phase B: reduce+sigmoid4.
__global__ __launch_bounds__(256) void scores_fused(
    const ushort_t* __restrict__ Aq, const ushort_t* __restrict__ Bx,
    float* __restrict__ P, ushort_t* __restrict__ OUT, float alpha)
{
  __shared__ __align__(16) ushort_t shA[64 * 64];
  __shared__ __align__(16) ushort_t shB[64 * 64];
  const int tid = threadIdx.x;
  const int l = tid & 63, w = tid >> 6;
  const int wr = w >> 1, wc = w & 1;
  const int row0 = blockIdx.y * 64, col0 = blockIdx.x * 64;
  const int z = blockIdx.z, zb = z >> 3, zk = z & 7;

  if (col0 <= row0 + 63){   // not fully causal-masked: compute partials
    const ushort_t* A = Aq + (size_t)zb * TT * DD;
    const ushort_t* B = Bx + (size_t)zb * TT * DD;
    const int kbeg = zk * (DD/8);
    f32x4 acc[2][2] = {};
    for (int kt = kbeg; kt < kbeg + DD/8; kt += 64){
      #pragma unroll
      for (int i = 0; i < 2; i++){
        int o = i*4096 + tid*16;
        int r = o >> 7, c = (o >> 4) & 7;
        int lc = c ^ (r & 7);
        async_copy16((char*)shA + o, A + (size_t)(row0 + r) * DD + kt + lc*8);
      }
      #pragma unroll
      for (int i = 0; i < 2; i++){
        int o = i*4096 + tid*16;
        int r = o >> 7, c = (o >> 4) & 7;
        int lc = c ^ (r & 7);
        async_copy16((char*)shB + o, B + (size_t)(col0 + r) * DD + kt + lc*8);
      }
      __syncthreads();
      #pragma unroll
      for (int kk = 0; kk < 2; kk++){
        s16x8 af[2], bfr[2];
        #pragma unroll
        for (int mi = 0; mi < 2; mi++){
          int r = wr*32 + mi*16 + (l & 15);
          int c = kk*4 + (l >> 4);
          af[mi] = *(const s16x8*)((const char*)shA + r*128 + ((c ^ (r & 7)) << 4));
        }
        #pragma unroll
        for (int ni = 0; ni < 2; ni++){
          int r = wc*32 + ni*16 + (l & 15);
          int c = kk*4 + (l >> 4);
          bfr[ni] = *(const s16x8*)((const char*)shB + r*128 + ((c ^ (r & 7)) << 4));
        }
        #pragma unroll
        for (int mi = 0; mi < 2; mi++)
          #pragma unroll
          for (int ni = 0; ni < 2; ni++)
            acc[mi][ni] = __builtin_amdgcn_mfma_f32_16x16x32_bf16(af[mi], bfr[ni], acc[mi][ni], 0, 0, 0);
      }
      __syncthreads();
    }
    float* Pz = P + (size_t)z * TT * TT;
    #pragma unroll
    for (int mi = 0; mi < 2; mi++)
      #pragma unroll
      for (int ni = 0; ni < 2; ni++)
        #pragma unroll
        for (int j = 0; j < 4; j++){
          int m = row0 + wr*32 + mi*16 + (l >> 4)*4 + j;
          int n = col0 + wc*32 + ni*16 + (l & 15);
          Pz[(size_t)m * TT + n] = acc[mi][ni][j];
        }
  }

  cg::this_grid().sync();

  // Phase B: reduce 8 partials -> sigmoid(4*alpha*s), causal, bf16
  const long MN = (long)TT * TT;
  long gid = (((long)blockIdx.z * 4 + blockIdx.y) * 4 + blockIdx.x) * 256 + tid;
  long nq = (NBAT * MN) / 4;   // 32768 quads; 65536 threads
  if (gid < nq){
    long idx = gid * 4;
    int b = (int)(idx / MN);
    long r = idx - (long)b * MN;
    int m = (int)(r / TT), n = (int)(r % TT);
    ushort4 ob;
    if (n > m){
      ob.x = 0; ob.y = 0; ob.z = 0; ob.w = 0;
    } else {
      float vv[4] = {0.f, 0.f, 0.f, 0.f};
      #pragma unroll
      for (int s = 0; s < 8; s++){
        float4 p4 = *(const float4*)&P[((long)(b*8 + s)) * MN + r];
        vv[0] += p4.x; vv[1] += p4.y; vv[2] += p4.z; vv[3] += p4.w;
      }
      ushort_t* pb = (ushort_t*)&ob;
      #pragma unroll
      for (int j = 0; j < 4; j++){
        float v = sigm(4.f * (vv[j] * alpha));
        if (n + j > m) v = 0.f;
        pb[j] = f2bf(v);
      }
    }
    *(ushort4*)&OUT[(long)b * MN + r] = ob;
  }
}

// ===================== cooperative: down split-K gemm + grid.sync + reduce(gelu) =====================
// grid (8,8,8): bx over CC/64, by over NTOK/64, z = zk. Phase B: sum + bias + gelu -> bf16.
__global__ __launch_bounds__(256) void down_fused(
    const ushort_t* __restrict__ At, const ushort_t* __restrict__ Bw,
    float* __restrict__ P, ushort_t* __restrict__ OUT, const float* __restrict__ bias)
{
  __shared__ __align__(16) ushort_t shA[64 * 64];
  __shared__ __align__(16) ushort_t shB[64 * 64];
  const int tid = threadIdx.x;
  const int l = tid & 63, w = tid >> 6;
  const int wr = w >> 1, wc = w & 1;
  const int row0 = blockIdx.y * 64, col0 = blockIdx.x * 64;
  const int zk = blockIdx.z;

  {
    const int kbeg = zk * (DD/8);
    f32x4 acc[2][2] = {};
    for (int kt = kbeg; kt < kbeg + DD/8; kt += 64){
      #pragma unroll
      for (int i = 0; i < 2; i++){
        int o = i*4096 + tid*16;
        int r = o >> 7, c = (o >> 4) & 7;
        int lc = c ^ (r & 7);
        async_copy16((char*)shA + o, At + (size_t)(row0 + r) * DD + kt + lc*8);
      }
      #pragma unroll
      for (int i = 0; i < 2; i++){
        int o = i*4096 + tid*16;
        int r = o >> 7, c = (o >> 4) & 7;
        int lc = c ^ (r & 7);
        async_copy16((char*)shB + o, Bw + (size_t)(col0 + r) * DD + kt + lc*8);
      }
      __syncthreads();
      #pragma unroll
      for (int kk = 0; kk < 2; kk++){
        s16x8 af[2], bfr[2];
        #pragma unroll
        for (int mi = 0; mi < 2; mi++){
          int r = wr*32 + mi*16 + (l & 15);
          int c = kk*4 + (l >> 4);
          af[mi] = *(const s16x8*)((const char*)shA + r*128 + ((c ^ (r & 7)) << 4));
        }
        #pragma unroll
        for (int ni = 0; ni < 2; ni++){
          int r = wc*32 + ni*16 + (l & 15);
          int c = kk*4 + (l >> 4);
          bfr[ni] = *(const s16x8*)((const char*)shB + r*128 + ((c ^ (r & 7)) << 4));
        }
        #pragma unroll
        for (int mi = 0; mi < 2; mi++)
          #pragma unroll
          for (int ni = 0; ni < 2; ni++)
            acc[mi][ni] = __builtin_amdgcn_mfma_f32_16x16x32_bf16(af[mi], bfr[ni], acc[mi][ni], 0, 0, 0);
      }
      __syncthreads();
    }
    float* Pz = P + (size_t)zk * NTOK * CC;
    #pragma unroll
    for (int mi = 0; mi < 2; mi++)
      #pragma unroll
      for (int ni = 0; ni < 2; ni++)
        #pragma unroll
        for (int j = 0; j < 4; j++){
          int m = row0 + wr*32 + mi*16 + (l >> 4)*4 + j;
          int n = col0 + wc*32 + ni*16 + (l & 15);
          Pz[(size_t)m * CC + n] = acc[mi][ni][j];
        }
  }

  cg::this_grid().sync();

  // Phase B: reduce 8 partials + bias + gelu -> bf16
  const long MN = (long)NTOK * CC;   // 262144
  long gid = (((long)blockIdx.z * 8 + blockIdx.y) * 8 + blockIdx.x) * 256 + tid;
  long nq = MN / 4;                  // 65536 quads; 131072 threads
  if (gid < nq){
    long r = gid * 4;
    int n = (int)(r % CC);
    float vv[4] = {0.f, 0.f, 0.f, 0.f};
    #pragma unroll
    for (int s = 0; s < 8; s++){
      float4 p4 = *(const float4*)&P[(long)s * MN + r];
      vv[0] += p4.x; vv[1] += p4.y; vv[2] += p4.z; vv[3] += p4.w;
    }
    ushort4 ob;
    ushort_t* pb = (ushort_t*)&ob;
    #pragma unroll
    for (int j = 0; j < 4; j++){
      float v = gelu(vv[j] + bias[n + j]);
      pb[j] = f2bf(v);
    }
    *(ushort4*)&OUT[r] = ob;
  }
}

// ===================== decoder: NT GEMM (r9-proven, frozen) =====================
__global__ __launch_bounds__(256) void gemm_ntf(const ushort_t* __restrict__ A,
    const float* __restrict__ B, float* __restrict__ C,
    const float* __restrict__ alpha_ptr)
{
  constexpr int BM = 256, BN = 64, FM = 8, FN = 2;
  constexpr int NXB = VV / BN;          // 500
  __shared__ __align__(16) ushort_t shA[BM * 64];
  __shared__ __align__(16) ushort_t shB[BN * 64];
  const int tid = threadIdx.x;
  const int l = tid & 63, w = tid >> 6;
  const int wr = w >> 1, wc = w & 1;
  int bid = blockIdx.x;                  // 0..999
  int swz = (bid & 7) * 125 + (bid >> 3);
  int bx = swz % NXB, by = swz / NXB;
  const int row0 = by * BM, col0 = bx * BN;

  f32x4 acc[FM][FN] = {};

  for (int kt = 0; kt < DD; kt += 64){
    #pragma unroll
    for (int i = 0; i < FM; i++){
      int o = i*4096 + tid*16;
      int r = o >> 7, c = (o >> 4) & 7;
      int lc = c ^ (r & 7);
      async_copy16((char*)shA + o, A + (size_t)(row0 + r) * DD + kt + lc*8);
    }
    #pragma unroll
    for (int i = 0; i < 4; i++){
      int idx4 = tid + i*256;
      int r = idx4 >> 4, kq = idx4 & 15;
      float4 v = *(const float4*)(B + (size_t)(col0 + r) * DD + kt + kq*4);
      u32 p0 = ((u32)f2bf(v.y) << 16) | (u32)f2bf(v.x);
      u32 p1 = ((u32)f2bf(v.w) << 16) | (u32)f2bf(v.z);
      int off = r*128 + (((kq >> 1) ^ (r & 7)) << 4) + ((kq & 1) << 3);
      uint2 pp; pp.x = p0; pp.y = p1;
      *(uint2*)((char*)shB + off) = pp;
    }
    __syncthreads();
    #pragma unroll
    for (int kk = 0; kk < 2; kk++){
      s16x8 af[FM], bfr[FN];
      #pragma unroll
      for (int mi = 0; mi < FM; mi++){
        int r = wr*(BM/2) + mi*16 + (l & 15);
        int c = kk*4 + (l >> 4);
        af[mi] = *(const s16x8*)((const char*)shA + r*128 + ((c ^ (r & 7)) << 4));
      }
      #pragma unroll
      for (int ni = 0; ni < FN; ni++){
        int r = wc*(BN/2) + ni*16 + (l & 15);
        int c = kk*4 + (l >> 4);
        bfr[ni] = *(const s16x8*)((const char*)shB + r*128 + ((c ^ (r & 7)) << 4));
      }
      #pragma unroll
      for (int mi = 0; mi < FM; mi++)
        #pragma unroll
        for (int ni = 0; ni < FN; ni++)
          acc[mi][ni] = __builtin_amdgcn_mfma_f32_16x16x32_bf16(af[mi], bfr[ni], acc[mi][ni], 0, 0, 0);
    }
    __syncthreads();
  }

  float alpha = *alpha_ptr;
  #pragma unroll
  for (int mi = 0; mi < FM; mi++)
    #pragma unroll
    for (int ni = 0; ni < FN; ni++)
      #pragma unroll
      for (int j = 0; j < 4; j++){
        int m = row0 + wr*(BM/2) + mi*16 + (l >> 4)*4 + j;
        int n = col0 + wc*(BN/2) + ni*16 + (l & 15);
        C[(size_t)m * VV + n] = acc[mi][ni][j] * alpha;
      }
}

extern "C" void kernel_launch(void* const* d_in, const int* in_sizes, int n_in,
                              void* d_out, int out_size, void* d_ws, size_t ws_size,
                              hipStream_t stream){
  const int*   idx        = (const int*)  d_in[0];
  const float* cb         = (const float*)d_in[1];
  const float* decay_lg   = (const float*)d_in[2];
  const float* bv_q       = (const float*)d_in[3];
  const float* bv_k       = (const float*)d_in[4];
  const float* bv_v       = (const float*)d_in[5];
  const float* rules      = (const float*)d_in[6];
  const float* query_bind = (const float*)d_in[7];
  const float* logic_gate = (const float*)d_in[8];
  const float* ln_mem_g   = (const float*)d_in[9];
  const float* ln_mem_b   = (const float*)d_in[10];
  const float* ln_attn_g  = (const float*)d_in[11];
  const float* ln_attn_b  = (const float*)d_in[12];
  const float* ln_logic_g = (const float*)d_in[13];
  const float* ln_logic_b = (const float*)d_in[14];
  const float* ctrl_g     = (const float*)d_in[15];
  const float* ctrl_b     = (const float*)d_in[16];
  const float* down_w     = (const float*)d_in[17];
  const float* down_b     = (const float*)d_in[18];
  const float* up_w       = (const float*)d_in[19];
  const float* up_b       = (const float*)d_in[20];
  const float* tl_gates   = (const float*)d_in[21];
  const float* tl_pos     = (const float*)d_in[22];
  const float* tl_g       = (const float*)d_in[23];
  const float* tl_b       = (const float*)d_in[24];
  const float* out_g      = (const float*)d_in[25];
  const float* out_b      = (const float*)d_in[26];
  const float* oscale     = (const float*)d_in[27];
  float* out = (float*)d_out;

  const size_t ND = (size_t)NTOK * DD;
  char* p = (char*)d_ws;
  auto alloc = [&](size_t bytes){ void* r = p; p += (bytes + 255) & ~(size_t)255; return r; };
  float*    X       = (float*)   alloc(ND * 4);
  float*    H       = (float*)   alloc(ND * 4);
  float*    T0      = (float*)   alloc(ND * 4);
  ushort_t* Xrb     = (ushort_t*)alloc(ND * 2);
  ushort_t* Xb      = (ushort_t*)alloc(ND * 2);
  ushort_t* Xqb     = (ushort_t*)alloc(ND * 2);
  ushort_t* Xvb     = (ushort_t*)alloc(ND * 2);
  ushort_t* T1b     = (ushort_t*)alloc(ND * 2);
  ushort_t* ATTNb   = (ushort_t*)alloc((size_t)NBAT * TT * TT * 2);
  ushort_t* CBbuf   = (ushort_t*)alloc((size_t)NTOK * CC * 2);
  float*    PP      = (float*)   alloc((size_t)16 * TT * TT * 4);    // scores partials (16 z)
  float*    PD      = (float*)   alloc((size_t)8 * NTOK * CC * 4);   // down partials
  float*    SQK     = (float*)   alloc((size_t)NBLK * DD * 4);
  float*    SV      = (float*)   alloc((size_t)NBLK * DD * 4);
  float*    SQB     = (float*)   alloc((size_t)NBLK * DD * 4);
  ushort_t* RLSb    = (ushort_t*)alloc((size_t)NBLK * RR * DD * 2);
  ushort_t* Adec    = (ushort_t*)alloc((size_t)NBLK * TT * TT * 2);
  ushort_t* down_wb = (ushort_t*)alloc((size_t)NBLK * CC * DD * 2);
  ushort_t* up_wb   = (ushort_t*)alloc((size_t)NBLK * DD * CC * 2);
  // total ~53 MiB

  const float RSD = 0.022097086912079608f;  // D^-0.5

  // ---- one-time prep (3 dispatches) ----
  sign_prep_kernel<<<3*NBLK + NBLK*RR + NBLK*TT, 256, 0, stream>>>(
      bv_q, bv_k, bv_v, query_bind, rules, decay_lg, SQK, SV, SQB, RLSb, Adec);
  cvt2_kernel<<<2048, 256, 0, stream>>>(down_w, down_wb, (long)NBLK*CC*DD/4,
                                        up_w, up_wb, (long)NBLK*DD*CC/4);
  encode_kernel<<<NTOK, 256, 0, stream>>>(idx, cb, X, Xrb);

  auto run_blocks = [&](){
    for (int i = 0; i < NBLK; i++){
      const size_t iD = (size_t)i * DD;
      // --- EMA as NN matmul (A lower-tri): T0 = Adec_i @ Xrb + X ---
      gemm_nn<<<dim3(DD/64, TT/64, NBAT), 256, 0, stream>>>(
          Adec + (size_t)i*TT*TT, Xrb, T0, TT, TT, DD, DD,
          0, (long)TT*DD, (long)TT*DD, X, 1);
      // --- LN_mem -> X (fp32), Xb, Xqb=y*SQK, Xvb=y*SV ---
      ln_kernel<<<NTOK, 256, 0, stream>>>(T0, ln_mem_g + iD, ln_mem_b + iD,
          X, Xb, SQK + iD, Xqb, SV + iD, Xvb);
      // --- cooperative: scores split-K8 + grid.sync + reduce(sigmoid4,causal) -> ATTNb ---
      {
        const ushort_t* a0 = Xqb; const ushort_t* a1 = Xb;
        float* a2 = PP; ushort_t* a3 = ATTNb; float a4 = RSD;
        void* args[] = { &a0, &a1, &a2, &a3, &a4 };
        hipLaunchCooperativeKernel((const void*)scores_fused,
            dim3(TT/64, TT/64, NBAT*8), dim3(256), args, 0, stream);
      }
      // --- att_out as NN matmul (A lower-tri): T0 = ATTN @ Xvb + X ---
      gemm_nn<<<dim3(DD/64, TT/64, NBAT), 256, 0, stream>>>(
          ATTNb, Xvb, T0, TT, TT, DD, DD,
          (long)TT*TT, (long)TT*DD, (long)TT*DD, X, 1);
      // --- mega-fused LN_attn + logic + gate + LN_logic + ctrl-LN ---
      fuse_logic_kernel<<<NTOK, 256, 0, stream>>>(T0,
          RLSb + (size_t)i*RR*DD, SQB + iD,
          ln_attn_g + iD, ln_attn_b + iD, logic_gate + i,
          ln_logic_g + iD, ln_logic_b + iD, ctrl_g + iD, ctrl_b + iD,
          X, T1b);
      // --- cooperative: MLP down split-K8 + grid.sync + reduce(bias,gelu) -> CBbuf ---
      {
        const ushort_t* a0 = T1b; const ushort_t* a1 = down_wb + (size_t)i*CC*DD;
        float* a2 = PD; ushort_t* a3 = CBbuf; const float* a4 = down_b + (size_t)i*CC;
        void* args[] = { &a0, &a1, &a2, &a3, &a4 };
        hipLaunchCooperativeKernel((const void*)down_fused,
            dim3(CC/64, NTOK/64, 8), dim3(256), args, 0, stream);
      }
      // --- MLP up: X = CBbuf @ up_w^T + bias + X  (+ bf16 mirror Xrb) ---
      gemm_nt<64,64,0,false><<<dim3(DD/64, NTOK/64, 1), 256, 0, stream>>>(
          CBbuf, up_wb + (size_t)i*DD*CC, X, CC, CC, CC, DD,
          0, 0, 0, up_b + iD, X, Xrb);
    }
  };

  run_blocks();
  tl_kernel<<<NTOK, 256, 0, stream>>>(X, H, nullptr, tl_g, tl_b,
      tl_pos + (size_t)1*DD, X, Xrb);
  run_blocks();
  tl_kernel<<<NTOK, 256, 0, stream>>>(X, H, tl_gates + 1, tl_g, tl_b,
      tl_pos + (size_t)2*DD, X, Xrb);
  run_blocks();
  tl_kernel<<<NTOK, 256, 0, stream>>>(X, H, tl_gates + 2, out_g, out_b,
      nullptr, nullptr, T1b);
  // logits = (LN(h) . cb^T) * output_scale — r9-proven decoder (frozen)
  gemm_ntf<<<(VV/64)*(NTOK/256), 256, 0, stream>>>(T1b, cb, out, oscale);
}

// Round 18
// 1055.531 us; speedup vs baseline: 2.3138x; 2.3138x over previous
//
#include <hip/hip_runtime.h>
#include <math.h>

#define TT   256
#define DD   2048
#define VV   32000
#define NBLK 4
#define CC   512
#define RR   32
#define MTT  3
#define NBAT 2
#define NTOK 512   // NBAT*TT

typedef unsigned int u32;
typedef unsigned short ushort_t;
typedef __attribute__((ext_vector_type(8))) short s16x8;
typedef __attribute__((ext_vector_type(4))) float f32x4;

__device__ __forceinline__ float sigm(float x){ return 1.0f/(1.0f+expf(-x)); }

__device__ __forceinline__ ushort_t f2bf(float f){
  u32 u = __float_as_uint(f);
  u32 r = (u + 0x7fffu + ((u >> 16) & 1u)) >> 16;
  return (ushort_t)r;
}
__device__ __forceinline__ float bf2f(ushort_t u){
  return __uint_as_float(((u32)u) << 16);
}

__device__ __forceinline__ void async_copy16(void* lds, const void* g){
  __builtin_amdgcn_global_load_lds((const __attribute__((address_space(1))) u32*)g,
                                   (__attribute__((address_space(3))) u32*)lds, 16, 0, 0);
}

__device__ __forceinline__ float block_sum256(float v){
  #pragma unroll
  for (int off = 32; off > 0; off >>= 1) v += __shfl_down(v, off);
  __shared__ float sh[4];
  __syncthreads();
  if ((threadIdx.x & 63) == 0) sh[threadIdx.x >> 6] = v;
  __syncthreads();
  return sh[0] + sh[1] + sh[2] + sh[3];
}

// fp32 -> bf16 for two tensors in one launch
__global__ __launch_bounds__(256) void cvt2_kernel(const float* __restrict__ a,
    ushort_t* __restrict__ oa, long na4,
    const float* __restrict__ b, ushort_t* __restrict__ ob, long nb4){
  long i = (long)blockIdx.x * 256 + threadIdx.x;
  long stride = (long)gridDim.x * 256;
  long tot = na4 + nb4;
  for (; i < tot; i += stride){
    const float* src = (i < na4) ? a : b;
    ushort_t* dst = (i < na4) ? oa : ob;
    long k = (i < na4) ? i : i - na4;
    float4 v = ((const float4*)src)[k];
    ushort4 o;
    o.x = f2bf(v.x); o.y = f2bf(v.y); o.z = f2bf(v.z); o.w = f2bf(v.w);
    ((ushort4*)dst)[k] = o;
  }
}

// one kernel for all sign-vector prep + Adec
__global__ __launch_bounds__(256) void sign_prep_kernel(
    const float* __restrict__ bv_q, const float* __restrict__ bv_k,
    const float* __restrict__ bv_v, const float* __restrict__ query_bind,
    const float* __restrict__ rules, const float* __restrict__ decay_logit,
    float* __restrict__ SQK, float* __restrict__ SV, float* __restrict__ SQB,
    ushort_t* __restrict__ RLSb, ushort_t* __restrict__ Adec){
  int b = blockIdx.x;
  if (b >= 3*NBLK + NBLK*RR){
    int e = b - (3*NBLK + NBLK*RR);
    int i = e >> 8, t = e & (TT - 1), s = threadIdx.x;
    float decay = sigm(decay_logit[i]);
    float l2 = log2f(decay);
    int ex = t - s;
    float v = (ex < 0) ? 0.f : exp2f((float)ex * l2);
    Adec[((size_t)i*TT + t)*TT + s] = f2bf(v);
    return;
  }
  if (b < NBLK){
    const float* q = bv_q + (size_t)b * DD;
    const float* k = bv_k + (size_t)b * DD;
    float sq = 0.f, sk = 0.f;
    #pragma unroll
    for (int j = 0; j < 8; j++){
      int d = threadIdx.x + j*256;
      sq += fabsf(q[d]); sk += fabsf(k[d]);
    }
    float aq = block_sum256(sq) * (1.f/DD);
    float ak = block_sum256(sk) * (1.f/DD);
    float a2 = aq * ak;
    float* o = SQK + (size_t)b * DD;
    #pragma unroll
    for (int j = 0; j < 8; j++){
      int d = threadIdx.x + j*256;
      o[d] = ((q[d] < 0.f) != (k[d] < 0.f)) ? -a2 : a2;
    }
    return;
  }
  const float* w; float* of = nullptr; ushort_t* ob = nullptr;
  if (b < 2*NBLK){ w = bv_v + (size_t)(b - NBLK) * DD; of = SV + (size_t)(b - NBLK) * DD; }
  else if (b < 3*NBLK){ w = query_bind + (size_t)(b - 2*NBLK) * DD; of = SQB + (size_t)(b - 2*NBLK) * DD; }
  else { int r = b - 3*NBLK; w = rules + (size_t)r * DD; ob = RLSb + (size_t)r * DD; }
  float s = 0.f;
  #pragma unroll
  for (int j = 0; j < 8; j++) s += fabsf(w[threadIdx.x + j*256]);
  float a = block_sum256(s) * (1.f/DD);
  #pragma unroll
  for (int j = 0; j < 8; j++){
    int d = threadIdx.x + j*256;
    float v = (w[d] < 0.f) ? -a : a;
    if (of) of[d] = v;
    else    ob[d] = f2bf(v);
  }
}

__global__ __launch_bounds__(256) void encode_kernel(const int* __restrict__ idx,
    const float* __restrict__ cb, float* __restrict__ X, ushort_t* __restrict__ Xrb){
  int token = blockIdx.x;
  int t = token & (TT - 1);
  size_t row = (size_t)idx[token] * DD;
  float s = 0.f;
  #pragma unroll
  for (int j = 0; j < 8; j++) s += fabsf(cb[row + threadIdx.x + j*256]);
  float a = block_sum256(s) * (1.f/DD);
  #pragma unroll
  for (int j = 0; j < 8; j++){
    int d = threadIdx.x + j*256;
    float w = cb[row + ((d - t) & (DD - 1))];
    float v = (w < 0.f) ? -a : a;
    X[(size_t)token * DD + d] = v;
    Xrb[(size_t)token * DD + d] = f2bf(v);
  }
}

// y=LN(A[row])*g+be; contiguous 8 elems/thread, fully vectorized loads/stores.
__global__ __launch_bounds__(256) void ln_kernel(const float* __restrict__ A,
    const float* __restrict__ g, const float* __restrict__ be,
    float* __restrict__ out, ushort_t* __restrict__ outb,
    const float* __restrict__ qscale, ushort_t* __restrict__ outq,
    const float* __restrict__ vscale, ushort_t* __restrict__ outv){
  size_t row = blockIdx.x;
  const float* a = A + row * DD;
  int d0 = threadIdx.x * 8;
  float v[8];
  *(float4*)&v[0] = *(const float4*)(a + d0);
  *(float4*)&v[4] = *(const float4*)(a + d0 + 4);
  float s = 0.f, ss = 0.f;
  #pragma unroll
  for (int j = 0; j < 8; j++){ s += v[j]; ss += v[j]*v[j]; }
  float mean = block_sum256(s) * (1.f/DD);
  float var  = block_sum256(ss) * (1.f/DD) - mean*mean;
  float inv  = rsqrtf(var + 1e-5f);
  float gv[8], bv[8];
  *(float4*)&gv[0] = *(const float4*)(g + d0);
  *(float4*)&gv[4] = *(const float4*)(g + d0 + 4);
  *(float4*)&bv[0] = *(const float4*)(be + d0);
  *(float4*)&bv[4] = *(const float4*)(be + d0 + 4);
  float y[8];
  #pragma unroll
  for (int j = 0; j < 8; j++) y[j] = (v[j] - mean) * inv * gv[j] + bv[j];
  if (out){
    *(float4*)(out + row*DD + d0)     = *(float4*)&y[0];
    *(float4*)(out + row*DD + d0 + 4) = *(float4*)&y[4];
  }
  if (outb){
    s16x8 o;
    #pragma unroll
    for (int j = 0; j < 8; j++) o[j] = (short)f2bf(y[j]);
    *(s16x8*)(outb + row*DD + d0) = o;
  }
  if (outq){
    float qv[8];
    *(float4*)&qv[0] = *(const float4*)(qscale + d0);
    *(float4*)&qv[4] = *(const float4*)(qscale + d0 + 4);
    s16x8 o;
    #pragma unroll
    for (int j = 0; j < 8; j++) o[j] = (short)f2bf(y[j] * qv[j]);
    *(s16x8*)(outq + row*DD + d0) = o;
  }
  if (outv){
    float vv[8];
    *(float4*)&vv[0] = *(const float4*)(vscale + d0);
    *(float4*)&vv[4] = *(const float4*)(vscale + d0 + 4);
    s16x8 o;
    #pragma unroll
    for (int j = 0; j < 8; j++) o[j] = (short)f2bf(y[j] * vv[j]);
    *(s16x8*)(outv + row*DD + d0) = o;
  }
}

// Mega-fused: LN_attn + logic + gate + LN_logic + ctrl-LN. One block per token.
__global__ __launch_bounds__(256) void fuse_logic_kernel(const float* __restrict__ T0,
    const ushort_t* __restrict__ RLSi, const float* __restrict__ SQBi,
    const float* __restrict__ g2, const float* __restrict__ b2,
    const float* __restrict__ gate_ptr,
    const float* __restrict__ g3, const float* __restrict__ b3,
    const float* __restrict__ g4, const float* __restrict__ b4,
    float* __restrict__ X, ushort_t* __restrict__ T1b){
  __shared__ float sh[256*33];
  __shared__ float red[8*32];
  __shared__ float rwsh[32];
  const float RSD = 0.022097086912079608f;
  int tid = threadIdx.x;
  size_t tok = blockIdx.x;
  const float* a = T0 + tok * DD;
  int d0 = tid * 8;
  float v[8];
  *(float4*)&v[0] = *(const float4*)(a + d0);
  *(float4*)&v[4] = *(const float4*)(a + d0 + 4);
  float s = 0.f, ss = 0.f;
  #pragma unroll
  for (int j = 0; j < 8; j++){ s += v[j]; ss += v[j]*v[j]; }
  float mean = block_sum256(s) * (1.f/DD);
  float var  = block_sum256(ss) * (1.f/DD) - mean*mean;
  float inv  = rsqrtf(var + 1e-5f);
  float g2v[8], b2v[8], sqv[8];
  *(float4*)&g2v[0] = *(const float4*)(g2 + d0);
  *(float4*)&g2v[4] = *(const float4*)(g2 + d0 + 4);
  *(float4*)&b2v[0] = *(const float4*)(b2 + d0);
  *(float4*)&b2v[4] = *(const float4*)(b2 + d0 + 4);
  *(float4*)&sqv[0] = *(const float4*)(SQBi + d0);
  *(float4*)&sqv[4] = *(const float4*)(SQBi + d0 + 4);
  float y2[8], xq[8];
  #pragma unroll
  for (int j = 0; j < 8; j++){
    y2[j] = (v[j] - mean) * inv * g2v[j] + b2v[j];
    xq[j] = y2[j] * sqv[j];
  }
  float aa[32];
  #pragma unroll 4
  for (int r = 0; r < 32; r++){
    s16x8 rv = *(const s16x8*)(RLSi + (size_t)r*DD + d0);
    float t = 0.f;
    #pragma unroll
    for (int j = 0; j < 8; j++)
      t = fmaf(xq[j], bf2f((ushort_t)rv[j]), t);
    aa[r] = t;
  }
  #pragma unroll
  for (int r = 0; r < 32; r++) sh[tid*33 + r] = aa[r];
  __syncthreads();
  {
    int r = tid & 31, gg = tid >> 5;
    float t = 0.f;
    #pragma unroll 8
    for (int i = 0; i < 32; i++) t += sh[(gg*32 + i)*33 + r];
    red[gg*32 + r] = t;
  }
  __syncthreads();
  if (tid < 32){
    float t = 0.f;
    #pragma unroll
    for (int gg = 0; gg < 8; gg++) t += red[gg*32 + tid];
    rwsh[tid] = sigm(4.f * RSD * t);
  }
  __syncthreads();
  float gate = sigm(*gate_ptr);
  float acc8[8] = {};
  #pragma unroll 4
  for (int r = 0; r < 32; r++){
    s16x8 rv = *(const s16x8*)(RLSi + (size_t)r*DD + d0);
    float w = rwsh[r];
    #pragma unroll
    for (int j = 0; j < 8; j++)
      acc8[j] = fmaf(w, bf2f((ushort_t)rv[j]), acc8[j]);
  }
  float p3[8]; s = 0.f; ss = 0.f;
  #pragma unroll
  for (int j = 0; j < 8; j++){
    float lo = y2[j] * acc8[j];
    p3[j] = y2[j] + gate * (lo - y2[j]);
    s += p3[j]; ss += p3[j]*p3[j];
  }
  mean = block_sum256(s) * (1.f/DD);
  var  = block_sum256(ss) * (1.f/DD) - mean*mean;
  inv  = rsqrtf(var + 1e-5f);
  float g3v[8], b3v[8];
  *(float4*)&g3v[0] = *(const float4*)(g3 + d0);
  *(float4*)&g3v[4] = *(const float4*)(g3 + d0 + 4);
  *(float4*)&b3v[0] = *(const float4*)(b3 + d0);
  *(float4*)&b3v[4] = *(const float4*)(b3 + d0 + 4);
  float y3[8]; s = 0.f; ss = 0.f;
  #pragma unroll
  for (int j = 0; j < 8; j++){
    y3[j] = (p3[j] - mean) * inv * g3v[j] + b3v[j];
    s += y3[j]; ss += y3[j]*y3[j];
  }
  *(float4*)(X + tok*DD + d0)     = *(float4*)&y3[0];
  *(float4*)(X + tok*DD + d0 + 4) = *(float4*)&y3[4];
  mean = block_sum256(s) * (1.f/DD);
  var  = block_sum256(ss) * (1.f/DD) - mean*mean;
  inv  = rsqrtf(var + 1e-5f);
  float g4v[8], b4v[8];
  *(float4*)&g4v[0] = *(const float4*)(g4 + d0);
  *(float4*)&g4v[4] = *(const float4*)(g4 + d0 + 4);
  *(float4*)&b4v[0] = *(const float4*)(b4 + d0);
  *(float4*)&b4v[4] = *(const float4*)(b4 + d0 + 4);
  s16x8 o;
  #pragma unroll
  for (int j = 0; j < 8; j++)
    o[j] = (short)f2bf((y3[j] - mean) * inv * g4v[j] + b4v[j]);
  *(s16x8*)(T1b + tok*DD + d0) = o;
}

// Thought-loop glue: contiguous vectorized
__global__ __launch_bounds__(256) void tl_kernel(const float* __restrict__ Xr,
    float* __restrict__ H, const float* __restrict__ gate_ptr,
    const float* __restrict__ g, const float* __restrict__ be,
    const float* __restrict__ pos,
    float* __restrict__ outX, ushort_t* __restrict__ outXb){
  size_t row = blockIdx.x;
  float gate = gate_ptr ? sigm(*gate_ptr) : 1.f;
  int d0 = threadIdx.x * 8;
  float xr[8];
  *(float4*)&xr[0] = *(const float4*)(Xr + row*DD + d0);
  *(float4*)&xr[4] = *(const float4*)(Xr + row*DD + d0 + 4);
  float v[8]; float s = 0.f, ss = 0.f;
  if (gate_ptr){
    float hv[8];
    *(float4*)&hv[0] = *(const float4*)(H + row*DD + d0);
    *(float4*)&hv[4] = *(const float4*)(H + row*DD + d0 + 4);
    #pragma unroll
    for (int j = 0; j < 8; j++) v[j] = hv[j] + gate * (xr[j] - hv[j]);
  } else {
    #pragma unroll
    for (int j = 0; j < 8; j++) v[j] = xr[j];
  }
  *(float4*)(H + row*DD + d0)     = *(float4*)&v[0];
  *(float4*)(H + row*DD + d0 + 4) = *(float4*)&v[4];
  #pragma unroll
  for (int j = 0; j < 8; j++){ s += v[j]; ss += v[j]*v[j]; }
  float mean = block_sum256(s) * (1.f/DD);
  float var  = block_sum256(ss) * (1.f/DD) - mean*mean;
  float inv  = rsqrtf(var + 1e-5f);
  float gv[8], bv[8];
  *(float4*)&gv[0] = *(const float4*)(g + d0);
  *(float4*)&gv[4] = *(const float4*)(g + d0 + 4);
  *(float4*)&bv[0] = *(const float4*)(be + d0);
  *(float4*)&bv[4] = *(const float4*)(be + d0 + 4);
  float y[8];
  #pragma unroll
  for (int j = 0; j < 8; j++) y[j] = (v[j] - mean) * inv * gv[j] + bv[j];
  if (pos){
    float pv[8];
    *(float4*)&pv[0] = *(const float4*)(pos + d0);
    *(float4*)&pv[4] = *(const float4*)(pos + d0 + 4);
    #pragma unroll
    for (int j = 0; j < 8; j++) y[j] += pv[j];
  }
  if (outX){
    *(float4*)(outX + row*DD + d0)     = *(float4*)&y[0];
    *(float4*)(outX + row*DD + d0 + 4) = *(float4*)&y[4];
  }
  if (outXb){
    s16x8 o;
    #pragma unroll
    for (int j = 0; j < 8; j++) o[j] = (short)f2bf(y[j]);
    *(s16x8*)(outXb + row*DD + d0) = o;
  }
}

// ===================== bf16 MFMA NT GEMM (single-buffer, +split-K, +mirror) =====================
template<int BM, int BN, int SPLITK, int ACT, bool CAUSAL, bool OUTBF>
__global__ __launch_bounds__(256) void gemm_nt(const ushort_t* __restrict__ A,
    const ushort_t* __restrict__ B, void* __restrict__ Cv,
    int K, int lda, int ldb, int ldc,
    long sA, long sB, long sC,
    const float* __restrict__ colscale, const float* __restrict__ bias,
    const float* __restrict__ res, ushort_t* __restrict__ mirror,
    const float* __restrict__ alpha_ptr, float alpha_c)
{
  constexpr int FM = BM / 32;
  constexpr int FN = BN / 32;
  __shared__ __align__(16) ushort_t shA[BM * 64];
  __shared__ __align__(16) ushort_t shB[BN * 64];
  const int tid = threadIdx.x;
  const int l = tid & 63, w = tid >> 6;
  const int wr = w >> 1, wc = w & 1;
  const int row0 = blockIdx.y * BM, col0 = blockIdx.x * BN;
  const int zb = blockIdx.z / SPLITK, zk = blockIdx.z % SPLITK;

  if (CAUSAL && col0 > row0 + BM - 1) return;  // consumer masks these

  A += (size_t)zb * sA;
  B += (size_t)zb * sB;
  const int kbeg = zk * (K / SPLITK), kend = kbeg + K / SPLITK;

  f32x4 acc[FM][FN] = {};

  for (int kt = kbeg; kt < kend; kt += 64){
    #pragma unroll
    for (int i = 0; i < BM/32; i++){
      int o = i*4096 + tid*16;
      int r = o >> 7, c = (o >> 4) & 7;
      int lc = c ^ (r & 7);
      async_copy16((char*)shA + o, A + (size_t)(row0 + r) * lda + kt + lc*8);
    }
    #pragma unroll
    for (int i = 0; i < BN/32; i++){
      int o = i*4096 + tid*16;
      int r = o >> 7, c = (o >> 4) & 7;
      int lc = c ^ (r & 7);
      async_copy16((char*)shB + o, B + (size_t)(col0 + r) * ldb + kt + lc*8);
    }
    __syncthreads();
    #pragma unroll
    for (int kk = 0; kk < 2; kk++){
      s16x8 af[FM], bfr[FN];
      #pragma unroll
      for (int mi = 0; mi < FM; mi++){
        int r = wr*(BM/2) + mi*16 + (l & 15);
        int c = kk*4 + (l >> 4);
        af[mi] = *(const s16x8*)((const char*)shA + r*128 + ((c ^ (r & 7)) << 4));
      }
      #pragma unroll
      for (int ni = 0; ni < FN; ni++){
        int r = wc*(BN/2) + ni*16 + (l & 15);
        int c = kk*4 + (l >> 4);
        bfr[ni] = *(const s16x8*)((const char*)shB + r*128 + ((c ^ (r & 7)) << 4));
      }
      #pragma unroll
      for (int mi = 0; mi < FM; mi++)
        #pragma unroll
        for (int ni = 0; ni < FN; ni++)
          acc[mi][ni] = __builtin_amdgcn_mfma_f32_16x16x32_bf16(af[mi], bfr[ni], acc[mi][ni], 0, 0, 0);
    }
    __syncthreads();
  }

  if (SPLITK > 1){
    float* P = (float*)Cv + (size_t)blockIdx.z * sC;
    #pragma unroll
    for (int mi = 0; mi < FM; mi++)
      #pragma unroll
      for (int ni = 0; ni < FN; ni++)
        #pragma unroll
        for (int j = 0; j < 4; j++){
          int m = row0 + wr*(BM/2) + mi*16 + (l >> 4)*4 + j;
          int n = col0 + wc*(BN/2) + ni*16 + (l & 15);
          P[(size_t)m * ldc + n] = acc[mi][ni][j];
        }
    return;
  }

  float alpha = alpha_c * (alpha_ptr ? *alpha_ptr : 1.f);
  float* Cf = (float*)Cv + (size_t)zb * sC;
  ushort_t* Cb = (ushort_t*)Cv + (size_t)zb * sC;
  const float* resz = res ? res + (size_t)zb * sC : nullptr;
  #pragma unroll
  for (int mi = 0; mi < FM; mi++){
    #pragma unroll
    for (int ni = 0; ni < FN; ni++){
      #pragma unroll
      for (int j = 0; j < 4; j++){
        int m = row0 + wr*(BM/2) + mi*16 + (l >> 4)*4 + j;
        int n = col0 + wc*(BN/2) + ni*16 + (l & 15);
        float v = acc[mi][ni][j] * alpha;
        if (colscale) v *= colscale[n];
        if (bias) v += bias[n];
        if (ACT == 1) v = sigm(4.f * v);
        else if (ACT == 2) v = 0.5f * v * (1.f + erff(v * 0.70710678118654752f));
        if (CAUSAL && n > m) v = 0.f;
        if (resz) v += resz[(size_t)m * ldc + n];
        if (OUTBF) Cb[(size_t)m * ldc + n] = f2bf(v);
        else       Cf[(size_t)m * ldc + n] = v;
        if (mirror) mirror[(size_t)m * ldc + n] = f2bf(v);
      }
    }
  }
}

// ===================== bf16 MFMA NN GEMM (register-staged transposed B) =====================
// tri!=0: A lower-triangular — K-loop stops at row0+64 (exact).
__global__ __launch_bounds__(256) void gemm_nn(const ushort_t* __restrict__ A,
    const ushort_t* __restrict__ B, float* __restrict__ C,
    int K, int lda, int ldb, int ldc,
    long sA, long sB, long sC,
    const float* __restrict__ res, int tri)
{
  __shared__ __align__(16) ushort_t shA[64 * 64];
  __shared__ __align__(16) ushort_t shB[64 * 64];
  const int tid = threadIdx.x;
  const int l = tid & 63, w = tid >> 6;
  const int wr = w >> 1, wc = w & 1;
  const int row0 = blockIdx.y * 64, col0 = blockIdx.x * 64;
  A += (size_t)blockIdx.z * sA;
  B += (size_t)blockIdx.z * sB;

  const int kb = tid & 63;
  const int nb0 = (tid >> 6) * 8;
  const int kend = tri ? (row0 + 64 < K ? row0 + 64 : K) : K;

  f32x4 acc[2][2] = {};

  for (int kt = 0; kt < kend; kt += 64){
    #pragma unroll
    for (int i = 0; i < 2; i++){
      int o = i*4096 + tid*16;
      int r = o >> 7, c = (o >> 4) & 7;
      int lc = c ^ (r & 7);
      async_copy16((char*)shA + o, A + (size_t)(row0 + r) * lda + kt + lc*8);
    }
    #pragma unroll
    for (int i = 0; i < 2; i++){
      int n0 = nb0 + i*32;
      s16x8 v = *(const s16x8*)(B + (size_t)(kt + kb) * ldb + col0 + n0);
      #pragma unroll
      for (int j = 0; j < 8; j++){
        int n = n0 + j;
        int off = n*128 + (((kb >> 3) ^ (n & 7)) << 4) + ((kb & 7) << 1);
        *(ushort_t*)((char*)shB + off) = (ushort_t)v[j];
      }
    }
    __syncthreads();
    #pragma unroll
    for (int kk = 0; kk < 2; kk++){
      s16x8 af[2], bfr[2];
      #pragma unroll
      for (int mi = 0; mi < 2; mi++){
        int r = wr*32 + mi*16 + (l & 15);
        int c = kk*4 + (l >> 4);
        af[mi] = *(const s16x8*)((const char*)shA + r*128 + ((c ^ (r & 7)) << 4));
      }
      #pragma unroll
      for (int ni = 0; ni < 2; ni++){
        int r = wc*32 + ni*16 + (l & 15);
        int c = kk*4 + (l >> 4);
        bfr[ni] = *(const s16x8*)((const char*)shB + r*128 + ((c ^ (r & 7)) << 4));
      }
      #pragma unroll
      for (int mi = 0; mi < 2; mi++)
        #pragma unroll
        for (int ni = 0; ni < 2; ni++)
          acc[mi][ni] = __builtin_amdgcn_mfma_f32_16x16x32_bf16(af[mi], bfr[ni], acc[mi][ni], 0, 0, 0);
    }
    __syncthreads();
  }

  float* Cf = C + (size_t)blockIdx.z * sC;
  const float* resz = res ? res + (size_t)blockIdx.z * sC : nullptr;
  #pragma unroll
  for (int mi = 0; mi < 2; mi++)
    #pragma unroll
    for (int ni = 0; ni < 2; ni++)
      #pragma unroll
      for (int j = 0; j < 4; j++){
        int m = row0 + wr*32 + mi*16 + (l >> 4)*4 + j;
        int n = col0 + wc*32 + ni*16 + (l & 15);
        float v = acc[mi][ni][j];
        if (resz) v += resz[(size_t)m * ldc + n];
        Cf[(size_t)m * ldc + n] = v;
      }
}

// split-K reduce + epilogue (coalesced; early-exit fully-masked causal quads)
template<int S, int ACT, bool CAUSAL, bool OUTBF>
__global__ __launch_bounds__(256) void reduce_epi(const float* __restrict__ P,
    void* __restrict__ outv, int M, int N, const float* __restrict__ bias, float alpha){
  long MN = (long)M * N;
  long idx = ((long)blockIdx.x * 256 + threadIdx.x) * 4;
  int b = (int)(idx / MN);
  long r = idx - (long)b * MN;
  int m = (int)(r / N), n = (int)(r % N);
  if (CAUSAL && n > m){
    if (OUTBF){ ushort4 z = {0,0,0,0}; *(ushort4*)&((ushort_t*)outv)[(long)b*MN + r] = z; }
    else      { float4 z = {0.f,0.f,0.f,0.f}; *(float4*)&((float*)outv)[(long)b*MN + r] = z; }
    return;
  }
  float vv[4] = {0.f, 0.f, 0.f, 0.f};
  #pragma unroll
  for (int s = 0; s < S; s++){
    float4 p = *(const float4*)&P[((long)(b*S + s)) * MN + r];
    vv[0] += p.x; vv[1] += p.y; vv[2] += p.z; vv[3] += p.w;
  }
  ushort4 ob; float4 of;
  float* po = (float*)&of;
  ushort_t* pb = (ushort_t*)&ob;
  #pragma unroll
  for (int j = 0; j < 4; j++){
    float v = vv[j] * alpha;
    if (bias) v += bias[n + j];
    if (ACT == 1) v = sigm(4.f * v);
    else if (ACT == 2) v = 0.5f * v * (1.f + erff(v * 0.70710678118654752f));
    if (CAUSAL && n + j > m) v = 0.f;
    po[j] = v; pb[j] = f2bf(v);
  }
  if (OUTBF) *(ushort4*)&((ushort_t*)outv)[(long)b*MN + r] = ob;
  else       *(float4*)&((float*)outv)[(long)b*MN + r] = of;
}

// ===================== decoder: NT GEMM (r9-proven, frozen) =====================
__global__ __launch_bounds__(256) void gemm_ntf(const ushort_t* __restrict__ A,
    const float* __restrict__ B, float* __restrict__ C,
    const float* __restrict__ alpha_ptr)
{
  constexpr int BM = 256, BN = 64, FM = 8, FN = 2;
  constexpr int NXB = VV / BN;          // 500
  __shared__ __align__(16) ushort_t shA[BM * 64];
  __shared__ __align__(16) ushort_t shB[BN * 64];
  const int tid = threadIdx.x;
  const int l = tid & 63, w = tid >> 6;
  const int wr = w >> 1, wc = w & 1;
  int bid = blockIdx.x;                  // 0..999
  int swz = (bid & 7) * 125 + (bid >> 3);
  int bx = swz % NXB, by = swz / NXB;
  const int row0 = by * BM, col0 = bx * BN;

  f32x4 acc[FM][FN] = {};

  for (int kt = 0; kt < DD; kt += 64){
    #pragma unroll
    for (int i = 0; i < FM; i++){
      int o = i*4096 + tid*16;
      int r = o >> 7, c = (o >> 4) & 7;
      int lc = c ^ (r & 7);
      async_copy16((char*)shA + o, A + (size_t)(row0 + r) * DD + kt + lc*8);
    }
    #pragma unroll
    for (int i = 0; i < 4; i++){
      int idx4 = tid + i*256;
      int r = idx4 >> 4, kq = idx4 & 15;
      float4 v = *(const float4*)(B + (size_t)(col0 + r) * DD + kt + kq*4);
      u32 p0 = ((u32)f2bf(v.y) << 16) | (u32)f2bf(v.x);
      u32 p1 = ((u32)f2bf(v.w) << 16) | (u32)f2bf(v.z);
      int off = r*128 + (((kq >> 1) ^ (r & 7)) << 4) + ((kq & 1) << 3);
      uint2 pp; pp.x = p0; pp.y = p1;
      *(uint2*)((char*)shB + off) = pp;
    }
    __syncthreads();
    #pragma unroll
    for (int kk = 0; kk < 2; kk++){
      s16x8 af[FM], bfr[FN];
      #pragma unroll
      for (int mi = 0; mi < FM; mi++){
        int r = wr*(BM/2) + mi*16 + (l & 15);
        int c = kk*4 + (l >> 4);
        af[mi] = *(const s16x8*)((const char*)shA + r*128 + ((c ^ (r & 7)) << 4));
      }
      #pragma unroll
      for (int ni = 0; ni < FN; ni++){
        int r = wc*(BN/2) + ni*16 + (l & 15);
        int c = kk*4 + (l >> 4);
        bfr[ni] = *(const s16x8*)((const char*)shB + r*128 + ((c ^ (r & 7)) << 4));
      }
      #pragma unroll
      for (int mi = 0; mi < FM; mi++)
        #pragma unroll
        for (int ni = 0; ni < FN; ni++)
          acc[mi][ni] = __builtin_amdgcn_mfma_f32_16x16x32_bf16(af[mi], bfr[ni], acc[mi][ni], 0, 0, 0);
    }
    __syncthreads();
  }

  float alpha = *alpha_ptr;
  #pragma unroll
  for (int mi = 0; mi < FM; mi++)
    #pragma unroll
    for (int ni = 0; ni < FN; ni++)
      #pragma unroll
      for (int j = 0; j < 4; j++){
        int m = row0 + wr*(BM/2) + mi*16 + (l >> 4)*4 + j;
        int n = col0 + wc*(BN/2) + ni*16 + (l & 15);
        C[(size_t)m * VV + n] = acc[mi][ni][j] * alpha;
      }
}

extern "C" void kernel_launch(void* const* d_in, const int* in_sizes, int n_in,
                              void* d_out, int out_size, void* d_ws, size_t ws_size,
                              hipStream_t stream){
  const int*   idx        = (const int*)  d_in[0];
  const float* cb         = (const float*)d_in[1];
  const float* decay_lg   = (const float*)d_in[2];
  const float* bv_q       = (const float*)d_in[3];
  const float* bv_k       = (const float*)d_in[4];
  const float* bv_v       = (const float*)d_in[5];
  const float* rules      = (const float*)d_in[6];
  const float* query_bind = (const float*)d_in[7];
  const float* logic_gate = (const float*)d_in[8];
  const float* ln_mem_g   = (const float*)d_in[9];
  const float* ln_mem_b   = (const float*)d_in[10];
  const float* ln_attn_g  = (const float*)d_in[11];
  const float* ln_attn_b  = (const float*)d_in[12];
  const float* ln_logic_g = (const float*)d_in[13];
  const float* ln_logic_b = (const float*)d_in[14];
  const float* ctrl_g     = (const float*)d_in[15];
  const float* ctrl_b     = (const float*)d_in[16];
  const float* down_w     = (const float*)d_in[17];
  const float* down_b     = (const float*)d_in[18];
  const float* up_w       = (const float*)d_in[19];
  const float* up_b       = (const float*)d_in[20];
  const float* tl_gates   = (const float*)d_in[21];
  const float* tl_pos     = (const float*)d_in[22];
  const float* tl_g       = (const float*)d_in[23];
  const float* tl_b       = (const float*)d_in[24];
  const float* out_g      = (const float*)d_in[25];
  const float* out_b      = (const float*)d_in[26];
  const float* oscale     = (const float*)d_in[27];
  float* out = (float*)d_out;

  const size_t ND = (size_t)NTOK * DD;
  char* p = (char*)d_ws;
  auto alloc = [&](size_t bytes){ void* r = p; p += (bytes + 255) & ~(size_t)255; return r; };
  float*    X       = (float*)   alloc(ND * 4);
  float*    H       = (float*)   alloc(ND * 4);
  float*    T0      = (float*)   alloc(ND * 4);
  ushort_t* Xrb     = (ushort_t*)alloc(ND * 2);
  ushort_t* Xb      = (ushort_t*)alloc(ND * 2);
  ushort_t* Xqb     = (ushort_t*)alloc(ND * 2);
  ushort_t* Xvb     = (ushort_t*)alloc(ND * 2);
  ushort_t* T1b     = (ushort_t*)alloc(ND * 2);
  ushort_t* ATTNb   = (ushort_t*)alloc((size_t)NBAT * TT * TT * 2);
  ushort_t* CBbuf   = (ushort_t*)alloc((size_t)NTOK * CC * 2);
  float*    PP      = (float*)   alloc((size_t)8 * NTOK * CC * 4);
  float*    SQK     = (float*)   alloc((size_t)NBLK * DD * 4);
  float*    SV      = (float*)   alloc((size_t)NBLK * DD * 4);
  float*    SQB     = (float*)   alloc((size_t)NBLK * DD * 4);
  ushort_t* RLSb    = (ushort_t*)alloc((size_t)NBLK * RR * DD * 2);
  ushort_t* Adec    = (ushort_t*)alloc((size_t)NBLK * TT * TT * 2);
  ushort_t* down_wb = (ushort_t*)alloc((size_t)NBLK * CC * DD * 2);
  ushort_t* up_wb   = (ushort_t*)alloc((size_t)NBLK * DD * CC * 2);
  // total ~48 MiB

  const float RSD = 0.022097086912079608f;  // D^-0.5

  // ---- one-time prep (3 dispatches) ----
  sign_prep_kernel<<<3*NBLK + NBLK*RR + NBLK*TT, 256, 0, stream>>>(
      bv_q, bv_k, bv_v, query_bind, rules, decay_lg, SQK, SV, SQB, RLSb, Adec);
  cvt2_kernel<<<2048, 256, 0, stream>>>(down_w, down_wb, (long)NBLK*CC*DD/4,
                                        up_w, up_wb, (long)NBLK*DD*CC/4);
  encode_kernel<<<NTOK, 256, 0, stream>>>(idx, cb, X, Xrb);

  auto run_blocks = [&](){
    for (int i = 0; i < NBLK; i++){
      const size_t iD = (size_t)i * DD;
      // --- EMA as NN matmul (A lower-tri): T0 = Adec_i @ Xrb + X ---
      gemm_nn<<<dim3(DD/64, TT/64, NBAT), 256, 0, stream>>>(
          Adec + (size_t)i*TT*TT, Xrb, T0, TT, TT, DD, DD,
          0, (long)TT*DD, (long)TT*DD, X, 1);
      // --- LN_mem -> X (fp32), Xb, Xqb=y*SQK, Xvb=y*SV ---
      ln_kernel<<<NTOK, 256, 0, stream>>>(T0, ln_mem_g + iD, ln_mem_b + iD,
          X, Xb, SQK + iD, Xqb, SV + iD, Xvb);
      // --- scores (split-K 8) + reduce(sigmoid4, causal) -> ATTNb ---
      gemm_nt<64,64,8,0,true,false><<<dim3(TT/64, TT/64, NBAT*8), 256, 0, stream>>>(
          Xqb, Xb, PP, DD, DD, DD, TT,
          (long)TT*DD, (long)TT*DD, (long)TT*TT,
          nullptr, nullptr, nullptr, nullptr, nullptr, 1.f);
      reduce_epi<8,1,true,true><<<(NBAT*TT*TT)/1024, 256, 0, stream>>>(
          PP, ATTNb, TT, TT, nullptr, RSD);
      // --- att_out as NN matmul (A lower-tri): T0 = ATTN @ Xvb + X ---
      gemm_nn<<<dim3(DD/64, TT/64, NBAT), 256, 0, stream>>>(
          ATTNb, Xvb, T0, TT, TT, DD, DD,
          (long)TT*TT, (long)TT*DD, (long)TT*DD, X, 1);
      // --- mega-fused LN_attn + logic + gate + LN_logic + ctrl-LN ---
      fuse_logic_kernel<<<NTOK, 256, 0, stream>>>(T0,
          RLSb + (size_t)i*RR*DD, SQB + iD,
          ln_attn_g + iD, ln_attn_b + iD, logic_gate + i,
          ln_logic_g + iD, ln_logic_b + iD, ctrl_g + iD, ctrl_b + iD,
          X, T1b);
      // --- MLP down (split-K 8) + reduce(bias, gelu) -> CBbuf ---
      gemm_nt<64,64,8,0,false,false><<<dim3(CC/64, NTOK/64, 8), 256, 0, stream>>>(
          T1b, down_wb + (size_t)i*CC*DD, PP, DD, DD, DD, CC,
          0, 0, (long)NTOK*CC,
          nullptr, nullptr, nullptr, nullptr, nullptr, 1.f);
      reduce_epi<8,2,false,true><<<(NTOK*CC)/1024, 256, 0, stream>>>(
          PP, CBbuf, NTOK, CC, down_b + (size_t)i*CC, 1.f);
      // --- MLP up: X = CBbuf @ up_w^T + bias + X  (+ bf16 mirror Xrb) ---
      gemm_nt<64,64,1,0,false,false><<<dim3(DD/64, NTOK/64, 1), 256, 0, stream>>>(
          CBbuf, up_wb + (size_t)i*DD*CC, X, CC, CC, CC, DD,
          0, 0, 0, nullptr, up_b + iD, X, Xrb, nullptr, 1.f);
    }
  };

  run_blocks();
  tl_kernel<<<NTOK, 256, 0, stream>>>(X, H, nullptr, tl_g, tl_b,
      tl_pos + (size_t)1*DD, X, Xrb);
  run_blocks();
  tl_kernel<<<NTOK, 256, 0, stream>>>(X, H, tl_gates + 1, tl_g, tl_b,
      tl_pos + (size_t)2*DD, X, Xrb);
  run_blocks();
  tl_kernel<<<NTOK, 256, 0, stream>>>(X, H, tl_gates + 2, out_g, out_b,
      nullptr, nullptr, T1b);
  // logits = (LN(h) . cb^T) * output_scale — r9-proven decoder (frozen)
  gemm_ntf<<<(VV/64)*(NTOK/256), 256, 0, stream>>>(T1b, cb, out, oscale);
}